// Round 11
// baseline (9816.158 us; speedup 1.0000x reference)
//
#include <hip/hip_runtime.h>
#include <hip/hip_fp16.h>

// Bidirectional GRU (B=64,S=1024,E=H=256) + FC/ReLU head.
// r11: COLUMN-SPLIT recurrence. 16 rec blocks = 2 dir x 4 bslice x 2 col-halves;
// each block owns 128 h-cols (per-SIMD MFMA and trans HALVED). Per step the two
// partner blocks exchange their h-halves through ws (hx, A-frag order) with a
// flag protocol: data = relaxed agent 2B atomics; __syncthreads (vmcnt drain +
// block order); tid0 release-stores flags[bid][s]; consumer acquires at step
// top and hides the 16 u32 loads under its own-half MFMA. hx parity-double-
// buffered; flags zeroed each launch by k_gx0. gx(c+1) still merged into
// k_step (blocks 16+). k_fc in place at the end.

typedef _Float16 f16x8 __attribute__((ext_vector_type(8)));
typedef _Float16 f16x4 __attribute__((ext_vector_type(4)));
typedef float    f32x4 __attribute__((ext_vector_type(4)));

#define MFMA(a,b,c) __builtin_amdgcn_mfma_f32_16x16x32_f16((a),(b),(c),0,0,0)
#define SWZ(r,c)  ((((r)*512)  + (c)) ^ (((r)&7)<<4))
#define SWZ2(r,c) ((((r)*1024) + (c)) ^ (((r)&7)<<4))
#define NLOG2E (-1.442695041f)
#define P2LOG2E (2.885390082f)

__device__ inline f16x8 pack8(float4 a, float4 b){
  f16x8 h;
  h[0]=(_Float16)a.x; h[1]=(_Float16)a.y; h[2]=(_Float16)a.z; h[3]=(_Float16)a.w;
  h[4]=(_Float16)b.x; h[5]=(_Float16)b.y; h[6]=(_Float16)b.z; h[7]=(_Float16)b.w;
  return h;
}
__device__ inline f16x8 pack8s(float4 a, float4 b, float s){
  f16x8 h;
  h[0]=(_Float16)(a.x*s); h[1]=(_Float16)(a.y*s); h[2]=(_Float16)(a.z*s); h[3]=(_Float16)(a.w*s);
  h[4]=(_Float16)(b.x*s); h[5]=(_Float16)(b.y*s); h[6]=(_Float16)(b.z*s); h[7]=(_Float16)(b.w*s);
  return h;
}
__device__ inline unsigned short h2u(_Float16 h){
  union { _Float16 f; unsigned short u; } c; c.f = h; return c.u;
}
union U8 { unsigned int u[4]; f16x8 v; };

// ---------------- gx body: 512 threads, one (t,dir); waves 4-7 stage-only ----------------
__device__ __forceinline__ void gx_body(
    char* smem, const float* __restrict__ X,
    const float* __restrict__ Wp, const float* __restrict__ bi, const float* __restrict__ bh,
    _Float16* __restrict__ gxc, int CT, int tc, int dir, int t)
{
  _Float16* As = (_Float16*)smem;            // 32KB
  _Float16* Bs = (_Float16*)(smem + 32768);  // 32KB
  const int tid = threadIdx.x;
  #pragma unroll
  for (int i = 0; i < 4; ++i) {              // stage A: rows = batch b, fixed t
    int c = tid + i*512, r = c >> 5, cc = c & 31;
    const float4* s4 = (const float4*)(X + ((size_t)r*1024 + t)*256 + cc*8);
    *(f16x8*)((char*)As + SWZ(r, cc*16)) = pack8(s4[0], s4[1]);
  }
  const int w = tid >> 6, l = tid & 63, lr = l & 15, g = l >> 4;
  const size_t obase = (((size_t)dir*CT + tc)*4 + (w & 3)) * (size_t)12288;
  #pragma unroll 1
  for (int nt = 0; nt < 12; ++nt) {
    __syncthreads();
    #pragma unroll
    for (int i = 0; i < 4; ++i) {            // stage B: W rows nt*64..+64
      int c = tid + i*512, r = c >> 5, cc = c & 31;
      const float4* s4 = (const float4*)(Wp + (size_t)(nt*64 + r)*256 + cc*8);
      *(f16x8*)((char*)Bs + SWZ(r, cc*16)) = pack8(s4[0], s4[1]);
    }
    __syncthreads();
    if (w < 4) {
      f32x4 acc[4];
      #pragma unroll
      for (int ct = 0; ct < 4; ++ct) acc[ct] = (f32x4){0.f,0.f,0.f,0.f};
      #pragma unroll
      for (int kk = 0; kk < 8; ++kk) {
        f16x8 af = *(const f16x8*)((const char*)As + SWZ(w*16 + lr, kk*64 + g*16));
        #pragma unroll
        for (int ct = 0; ct < 4; ++ct) {
          f16x8 bfr = *(const f16x8*)((const char*)Bs + SWZ(ct*16 + lr, kk*64 + g*16));
          acc[ct] = MFMA(af, bfr, acc[ct]);
        }
      }
      #pragma unroll
      for (int ct = 0; ct < 4; ++ct) {       // consumer layout [tid512][3][8]
        const int col = nt*64 + ct*16 + lr;
        const int gate = col >> 8;
        const float sc = (gate == 2) ? P2LOG2E : NLOG2E;
        const float bv = bi[col] + (gate < 2 ? bh[col] : 0.f);
        const int j = col & 255;
        const int tid2 = (j>>5)*64 + g*16 + (j&15);
        const int off = ((j>>4)&1)*4;
        f16x4 v;
        #pragma unroll
        for (int q = 0; q < 4; ++q) v[q] = (_Float16)((acc[ct][q] + bv)*sc);
        *(f16x4*)(gxc + obase + (size_t)tid2*24 + gate*8 + off) = v;
      }
    }
  }
}

// ---------------- gx prologue kernel (chunk 0) + flag clear ----------------
__global__ __launch_bounds__(512, 2) void k_gx0(
    const float* __restrict__ X,
    const float* __restrict__ Wf, const float* __restrict__ bihf, const float* __restrict__ bhhf,
    const float* __restrict__ Wb, const float* __restrict__ bihb, const float* __restrict__ bhhb,
    _Float16* __restrict__ gxc, int CT, int sbase, unsigned* __restrict__ flags)
{
  __shared__ char smem[65536];
  const int tc = blockIdx.x, dir = blockIdx.y;
  if (dir == 0 && tc < 16) {                 // zero flags[16][1024] before any k_step
    unsigned* fl = flags + (size_t)tc*1024;
    for (int i = threadIdx.x; i < 1024; i += 512) fl[i] = 0;
  }
  const int p = sbase + tc;
  const int t = dir ? (1023 - p) : p;
  gx_body(smem, X, dir ? Wb : Wf, dir ? bihb : bihf, dir ? bhhb : bhhf,
          gxc, CT, tc, dir, t);
}

// ---------------- merged step: rec(chunk c, col-split) + gx(chunk c+1) ----------------
__global__ __launch_bounds__(512, 2) void k_step(
    const float* __restrict__ Whh_f, const float* __restrict__ bhh_f,
    const float* __restrict__ Whh_b, const float* __restrict__ bhh_b,
    const _Float16* __restrict__ gxin, float* __restrict__ wsh,
    _Float16* __restrict__ out16, float* __restrict__ hidden,
    char* __restrict__ hxbuf, unsigned* __restrict__ flags,
    int CT, int sbase,
    const float* __restrict__ X,
    const float* __restrict__ Wf, const float* __restrict__ bihf, const float* __restrict__ bhhf,
    const float* __restrict__ Wb, const float* __restrict__ bihb, const float* __restrict__ bhhb,
    _Float16* __restrict__ gxout, int sbase_gx, int gx_valid)
{
  __shared__ char smem[65536];
  if (blockIdx.x >= 16) {                    // ---- gx role: chunk c+1 ----
    if (!gx_valid) return;
    const int b = blockIdx.x - 16;
    const int tc = b >> 1, dir = b & 1;
    const int p = sbase_gx + tc;
    const int t = dir ? (1023 - p) : p;
    gx_body(smem, X, dir ? Wb : Wf, dir ? bihb : bihf, dir ? bhhb : bhhf,
            gxout, CT, tc, dir, t);
    return;
  }
  // ---- recurrence role: block owns (dir, bslice, col-half ch) ----
  const int ch  = blockIdx.x >> 3;           // col half 0/1
  const int pr  = blockIdx.x & 7;            // pair id
  const int dir = pr & 1;
  const int bsl = pr >> 1;
  const int bbase = bsl * 16;
  const int chb = ch << 7;                   // 128*ch
  const float* __restrict__ Whh = dir ? Whh_b : Whh_f;
  const float* __restrict__ bhh = dir ? bhh_b : bhh_f;
  const int tid = threadIdx.x, w = tid >> 6, l = tid & 63;
  const int lr = l & 15, g = l >> 4;
  const int j0 = chb + w*16;                 // +lr = my h column
  f16x8 wf[3][8];                            // B-frag: W[col=gate*256+j0+lr][k], pre-scaled
  #pragma unroll
  for (int ct = 0; ct < 3; ++ct) {
    const int colg = ct*256 + j0 + lr;
    const float scl = (ct < 2) ? NLOG2E : P2LOG2E;
    #pragma unroll
    for (int kk = 0; kk < 8; ++kk) {
      const float4* s4 = (const float4*)(Whh + (size_t)colg*256 + kk*32 + g*8);
      wf[ct][kk] = pack8s(s4[0], s4[1], scl);
    }
  }
  const float bn = P2LOG2E * bhh[512 + j0 + lr];
  char* const afp = smem + l*16;             // A-frag read base (16x256 tile, ping-pong 8KB)
  char* const hwp = smem + (ch*16 + w*2 + (lr>>3))*256 + g*64 + (lr&7)*2;  // own-half write
  float hold[4];
  if (sbase == 0) {
    *(int4*)(smem + tid*16) = make_int4(0,0,0,0);        // hs[0] := 0 (8KB exact)
    #pragma unroll
    for (int q = 0; q < 4; ++q) hold[q] = 0.f;
  } else {                                   // restore FULL h tile from previous chunk
    const int r = tid >> 5, kq = tid & 31;
    const float4* s4 = (const float4*)(wsh + ((size_t)(dir*64 + bbase + r))*256 + kq*8);
    *(f16x8*)(smem + (kq>>2)*1024 + (((kq&3)*16) + r)*16) = pack8(s4[0], s4[1]);
    #pragma unroll
    for (int q = 0; q < 4; ++q)
      hold[q] = wsh[((size_t)(dir*64 + bbase + g*4 + q))*256 + j0 + lr];
  }
  __syncthreads();

  const int t0 = dir ? (1023 - sbase) : sbase;
  char* optr = (char*)out16 + ((size_t)t0*64 + bbase + g*4)*1024
             + (size_t)(dir*256 + j0 + lr)*2;
  const ptrdiff_t ostep = dir ? -(ptrdiff_t)65536 : (ptrdiff_t)65536;
  const int tid2 = (ch*4 + (w>>1))*64 + g*16 + lr;       // gx consumer index
  const _Float16* gp = gxin + ((size_t)(dir*CT)*4 + bsl)*12288
                     + (size_t)tid2*24 + (w&1)*4;
  char* const hxme = hxbuf + (size_t)(pr*2 + ch)*8192
                   + (w*2 + (lr>>3))*256 + g*64 + (lr&7)*2;
  const char* const hxot = hxbuf + (size_t)(pr*2 + (ch^1))*8192;
  unsigned* const myflag = flags + (size_t)blockIdx.x*1024;
  unsigned* const pflag  = flags + (size_t)(blockIdx.x ^ 8)*1024;
  int sabs = sbase;

// One step: gx loads -> [spin partner flag(s-1), issue other-half loads] ->
// own-K MFMA (hides load latency) -> other-K MFMA -> gates -> stores (LDS own
// + out16 + hx atomics) -> __syncthreads (vmcnt drain + order) -> tid0 flag.
#define REC_STEP(RB, FIRST)                                                        \
  {                                                                                \
    const f16x4 gv0 = *(const f16x4*)(gp);                                         \
    const f16x4 gv1 = *(const f16x4*)(gp + 8);                                     \
    const f16x4 gv2 = *(const f16x4*)(gp + 16);                                    \
    gp += 49152;                                                                   \
    unsigned od[4][4];                                                             \
    if (!(FIRST)) {                                                                \
      while (!__hip_atomic_load(pflag + (sabs-1), __ATOMIC_ACQUIRE,                \
                                __HIP_MEMORY_SCOPE_AGENT))                         \
        __builtin_amdgcn_s_sleep(1);                                               \
      const char* ob = hxot + ((sabs-1)&1)*4096 + l*16;                            \
      _Pragma("unroll")                                                            \
      for (int kko = 0; kko < 4; ++kko)                                            \
        _Pragma("unroll")                                                          \
        for (int d = 0; d < 4; ++d)                                                \
          od[kko][d] = __hip_atomic_load(                                          \
              (const unsigned*)(ob + kko*1024 + d*4),                              \
              __ATOMIC_RELAXED, __HIP_MEMORY_SCOPE_AGENT);                         \
    }                                                                              \
    f32x4 ar = (f32x4){0.f,0.f,0.f,0.f};                                           \
    f32x4 az = (f32x4){0.f,0.f,0.f,0.f};                                           \
    f32x4 an = (f32x4){bn,bn,bn,bn};                                               \
    _Pragma("unroll")                                                              \
    for (int kko = 0; kko < 4; ++kko) {      /* own-K (local LDS) */               \
      const int kkg = ch*4 + kko;                                                  \
      const f16x8 af = *(const f16x8*)(afp + (RB)*8192 + kkg*1024);                \
      ar = MFMA(af, wf[0][kkg], ar);                                               \
      az = MFMA(af, wf[1][kkg], az);                                               \
      an = MFMA(af, wf[2][kkg], an);                                               \
    }                                                                              \
    _Pragma("unroll")                                                              \
    for (int kko = 0; kko < 4; ++kko) {      /* other-K (LDS at chunk start) */    \
      const int kkg = (ch^1)*4 + kko;                                              \
      f16x8 af;                                                                    \
      if (FIRST) {                                                                 \
        af = *(const f16x8*)(afp + (RB)*8192 + kkg*1024);                          \
      } else {                                                                     \
        U8 u; u.u[0]=od[kko][0]; u.u[1]=od[kko][1];                                \
        u.u[2]=od[kko][2]; u.u[3]=od[kko][3];                                      \
        af = u.v;                                                                  \
      }                                                                            \
      ar = MFMA(af, wf[0][kkg], ar);                                               \
      az = MFMA(af, wf[1][kkg], az);                                               \
      an = MFMA(af, wf[2][kkg], an);                                               \
    }                                                                              \
    _Pragma("unroll")                                                              \
    for (int q = 0; q < 4; ++q) {                                                  \
      const float rv = __builtin_amdgcn_rcpf(                                      \
          1.f + __builtin_amdgcn_exp2f((float)gv0[q] + ar[q]));                    \
      const float zv = __builtin_amdgcn_rcpf(                                      \
          1.f + __builtin_amdgcn_exp2f((float)gv1[q] + az[q]));                    \
      const float nv = __builtin_fmaf(-2.f, __builtin_amdgcn_rcpf(                 \
          1.f + __builtin_amdgcn_exp2f(                                            \
              __builtin_fmaf(rv, an[q], (float)gv2[q]))), 1.f);                    \
      const float h = __builtin_fmaf(zv, hold[q] - nv, nv);                        \
      hold[q] = h;                                                                 \
      const _Float16 hf = (_Float16)h;                                             \
      *(_Float16*)(hwp + ((RB)^1)*8192 + q*16) = hf;                               \
      *(_Float16*)(optr + q*1024) = hf;                                            \
      __hip_atomic_store((unsigned short*)(hxme + (sabs&1)*4096 + q*16),           \
                         h2u(hf), __ATOMIC_RELAXED, __HIP_MEMORY_SCOPE_AGENT);     \
    }                                                                              \
    optr += ostep;                                                                 \
    __syncthreads();                         /* drains vmcnt+lgkm, orders block */ \
    if (tid == 0)                                                                  \
      __hip_atomic_store(myflag + sabs, 1u, __ATOMIC_RELEASE,                      \
                         __HIP_MEMORY_SCOPE_AGENT);                                \
    ++sabs;                                                                        \
  }

  REC_STEP(0, 1)                             // sc = 0: other half from restored LDS
  #pragma unroll 1
  for (int sc = 1; sc + 1 < CT; sc += 2) {
    REC_STEP(1, 0)
    REC_STEP(0, 0)
  }
  REC_STEP(1, 0)                             // sc = CT-1
#undef REC_STEP

  if (sbase + CT == 1024) {                  // final h -> hidden output (own cols)
    #pragma unroll
    for (int q = 0; q < 4; ++q)
      hidden[((size_t)(dir*64 + bbase + g*4 + q))*256 + j0 + lr] = hold[q];
  } else {                                   // persist own cols for next chunk
    #pragma unroll
    for (int q = 0; q < 4; ++q)
      wsh[((size_t)(dir*64 + bbase + g*4 + q))*256 + j0 + lr] = hold[q];
  }
}

// ---------------- FC in place: relu(concat_f16 @ W_fc^T + b) -> f32 ----------------
__global__ __launch_bounds__(256) void k_fc(
    const _Float16* __restrict__ h16, const float* __restrict__ Wfc,
    const float* __restrict__ bfc, float* __restrict__ out)
{
  const int mt = blockIdx.x;
  __shared__ _Float16 As[64*512];            // 64KB
  const int tid = threadIdx.x, w = tid >> 6, l = tid & 63;
  const int lr = l & 15, g = l >> 4;
  #pragma unroll
  for (int i = 0; i < 16; ++i) {
    int c = tid + i*256, r = c >> 6, cc = c & 63;
    *(int4*)((char*)As + SWZ2(r, cc*16)) =
        *(const int4*)((const char*)h16 + ((size_t)mt*64 + r)*1024 + cc*16);
  }
  __syncthreads();                           // all h16 reads drained before any store
  #pragma unroll 1
  for (int nt = 0; nt < 4; ++nt) {
    f32x4 acc[4];
    #pragma unroll
    for (int ct = 0; ct < 4; ++ct) acc[ct] = (f32x4){0.f,0.f,0.f,0.f};
    #pragma unroll 2
    for (int kk = 0; kk < 16; ++kk) {
      f16x8 af = *(const f16x8*)((const char*)As + SWZ2(w*16 + lr, kk*64 + g*16));
      #pragma unroll
      for (int ct = 0; ct < 4; ++ct) {
        const float4* s4 = (const float4*)(Wfc + (size_t)(nt*64 + ct*16 + lr)*512 + kk*32 + g*8);
        acc[ct] = MFMA(af, pack8(s4[0], s4[1]), acc[ct]);
      }
    }
    #pragma unroll
    for (int ct = 0; ct < 4; ++ct) {
      const int col = nt*64 + ct*16 + lr;
      const float bv = bfc[col];
      #pragma unroll
      for (int q = 0; q < 4; ++q) {
        const int row = w*16 + g*4 + q;
        out[((size_t)mt*64 + row)*256 + col] = fmaxf(acc[ct][q] + bv, 0.f);
      }
    }
  }
}

extern "C" void kernel_launch(void* const* d_in, const int* in_sizes, int n_in,
                              void* d_out, int out_size, void* d_ws, size_t ws_size,
                              hipStream_t stream) {
  const float* X      = (const float*)d_in[0];
  const float* W_ih_f = (const float*)d_in[1];
  const float* W_hh_f = (const float*)d_in[2];
  const float* b_ih_f = (const float*)d_in[3];
  const float* b_hh_f = (const float*)d_in[4];
  const float* W_ih_b = (const float*)d_in[5];
  const float* W_hh_b = (const float*)d_in[6];
  const float* b_ih_b = (const float*)d_in[7];
  const float* b_hh_b = (const float*)d_in[8];
  const float* W_fc   = (const float*)d_in[9];
  const float* b_fc   = (const float*)d_in[10];

  // ws: buf0 | buf1 | wsh 128KB | hx 128KB | flags 64KB
  int CT = 256;
  while (CT > 8 && (2*(size_t)CT*196608 + 327680) > ws_size) CT >>= 1;
  const size_t CTB = (size_t)CT*196608;
  _Float16* buf0  = (_Float16*)d_ws;
  _Float16* buf1  = (_Float16*)((char*)d_ws + CTB);
  float*    wsh   = (float*)((char*)d_ws + 2*CTB);
  char*     hx    = (char*)d_ws + 2*CTB + 131072;
  unsigned* flags = (unsigned*)((char*)d_ws + 2*CTB + 262144);

  _Float16* h16   = (_Float16*)d_out;                  // [1024][64][512] f16 (in-place)
  float*    out   = (float*)d_out;                     // [1024][64][256] f32
  float*    hidden= (float*)d_out + (size_t)1024*64*256;

  const int NC = 1024 / CT;
  k_gx0<<<dim3(CT, 2), dim3(512), 0, stream>>>(X, W_ih_f, b_ih_f, b_hh_f,
                                               W_ih_b, b_ih_b, b_hh_b, buf0, CT, 0, flags);
  for (int c = 0; c < NC; ++c) {
    _Float16* bin  = (c & 1) ? buf1 : buf0;
    _Float16* bout = (c & 1) ? buf0 : buf1;
    k_step<<<dim3(16 + 2*CT), dim3(512), 0, stream>>>(
        W_hh_f, b_hh_f, W_hh_b, b_hh_b, bin, wsh, h16, hidden, hx, flags,
        CT, c*CT,
        X, W_ih_f, b_ih_f, b_hh_f, W_ih_b, b_ih_b, b_hh_b,
        bout, (c+1)*CT, (c < NC-1) ? 1 : 0);
  }
  k_fc<<<dim3(1024), dim3(256), 0, stream>>>(h16, W_fc, b_fc, out);
}

// Round 12
// 3201.879 us; speedup vs baseline: 3.0657x; 3.0657x over previous
//
#include <hip/hip_runtime.h>
#include <hip/hip_fp16.h>

// Bidirectional GRU (B=64,S=1024,E=H=256) + FC/ReLU head.
// r12: column-split recurrence v2. 16 rec blocks = 2 col-halves x (2dir x 4bsl);
// each owns 128 h-cols (per-SIMD MFMA+trans halved vs r10). Cross-block h
// exchange: own-half LDS tile copied linearly (8B/thread) to ws via native u64
// relaxed agent atomics after bar#1; bar#2 acks; tid0 release-stores flag;
// consumer spins (relaxed, no sleep) + acquire fence + u64 loads + bit_cast,
// hidden under own-half MFMA. ALL register arrays statically indexed (r11's
// fatal wf[ct][runtime] scratch spill removed). gx(c+1) merged into k_step
// (blocks 16+); k_fc in place at the end.

typedef _Float16 f16x8 __attribute__((ext_vector_type(8)));
typedef _Float16 f16x4 __attribute__((ext_vector_type(4)));
typedef float    f32x4 __attribute__((ext_vector_type(4)));
typedef unsigned long long u64_t;
typedef unsigned long long u64x2 __attribute__((ext_vector_type(2)));

#define MFMA(a,b,c) __builtin_amdgcn_mfma_f32_16x16x32_f16((a),(b),(c),0,0,0)
#define SWZ(r,c)  ((((r)*512)  + (c)) ^ (((r)&7)<<4))
#define SWZ2(r,c) ((((r)*1024) + (c)) ^ (((r)&7)<<4))
#define NLOG2E (-1.442695041f)
#define P2LOG2E (2.885390082f)

__device__ inline f16x8 pack8(float4 a, float4 b){
  f16x8 h;
  h[0]=(_Float16)a.x; h[1]=(_Float16)a.y; h[2]=(_Float16)a.z; h[3]=(_Float16)a.w;
  h[4]=(_Float16)b.x; h[5]=(_Float16)b.y; h[6]=(_Float16)b.z; h[7]=(_Float16)b.w;
  return h;
}
__device__ inline f16x8 pack8s(float4 a, float4 b, float s){
  f16x8 h;
  h[0]=(_Float16)(a.x*s); h[1]=(_Float16)(a.y*s); h[2]=(_Float16)(a.z*s); h[3]=(_Float16)(a.w*s);
  h[4]=(_Float16)(b.x*s); h[5]=(_Float16)(b.y*s); h[6]=(_Float16)(b.z*s); h[7]=(_Float16)(b.w*s);
  return h;
}

// ---------------- gx body: 512 threads, one (t,dir); waves 4-7 stage-only ----------------
__device__ __forceinline__ void gx_body(
    char* smem, const float* __restrict__ X,
    const float* __restrict__ Wp, const float* __restrict__ bi, const float* __restrict__ bh,
    _Float16* __restrict__ gxc, int CT, int tc, int dir, int t)
{
  _Float16* As = (_Float16*)smem;            // 32KB
  _Float16* Bs = (_Float16*)(smem + 32768);  // 32KB
  const int tid = threadIdx.x;
  #pragma unroll
  for (int i = 0; i < 4; ++i) {              // stage A: rows = batch b, fixed t
    int c = tid + i*512, r = c >> 5, cc = c & 31;
    const float4* s4 = (const float4*)(X + ((size_t)r*1024 + t)*256 + cc*8);
    *(f16x8*)((char*)As + SWZ(r, cc*16)) = pack8(s4[0], s4[1]);
  }
  const int w = tid >> 6, l = tid & 63, lr = l & 15, g = l >> 4;
  const size_t obase = (((size_t)dir*CT + tc)*4 + (w & 3)) * (size_t)12288;
  #pragma unroll 1
  for (int nt = 0; nt < 12; ++nt) {
    __syncthreads();
    #pragma unroll
    for (int i = 0; i < 4; ++i) {            // stage B: W rows nt*64..+64
      int c = tid + i*512, r = c >> 5, cc = c & 31;
      const float4* s4 = (const float4*)(Wp + (size_t)(nt*64 + r)*256 + cc*8);
      *(f16x8*)((char*)Bs + SWZ(r, cc*16)) = pack8(s4[0], s4[1]);
    }
    __syncthreads();
    if (w < 4) {
      f32x4 acc[4];
      #pragma unroll
      for (int ct = 0; ct < 4; ++ct) acc[ct] = (f32x4){0.f,0.f,0.f,0.f};
      #pragma unroll
      for (int kk = 0; kk < 8; ++kk) {
        f16x8 af = *(const f16x8*)((const char*)As + SWZ(w*16 + lr, kk*64 + g*16));
        #pragma unroll
        for (int ct = 0; ct < 4; ++ct) {
          f16x8 bfr = *(const f16x8*)((const char*)Bs + SWZ(ct*16 + lr, kk*64 + g*16));
          acc[ct] = MFMA(af, bfr, acc[ct]);
        }
      }
      #pragma unroll
      for (int ct = 0; ct < 4; ++ct) {       // consumer layout [tid512][3][8]
        const int col = nt*64 + ct*16 + lr;
        const int gate = col >> 8;
        const float sc = (gate == 2) ? P2LOG2E : NLOG2E;
        const float bv = bi[col] + (gate < 2 ? bh[col] : 0.f);
        const int j = col & 255;
        const int tid2 = (j>>5)*64 + g*16 + (j&15);
        const int off = ((j>>4)&1)*4;
        f16x4 v;
        #pragma unroll
        for (int q = 0; q < 4; ++q) v[q] = (_Float16)((acc[ct][q] + bv)*sc);
        *(f16x4*)(gxc + obase + (size_t)tid2*24 + gate*8 + off) = v;
      }
    }
  }
}

// ---------------- gx prologue kernel (chunk 0) + flag clear ----------------
__global__ __launch_bounds__(512, 2) void k_gx0(
    const float* __restrict__ X,
    const float* __restrict__ Wf, const float* __restrict__ bihf, const float* __restrict__ bhhf,
    const float* __restrict__ Wb, const float* __restrict__ bihb, const float* __restrict__ bhhb,
    _Float16* __restrict__ gxc, int CT, int sbase, unsigned* __restrict__ flags)
{
  __shared__ char smem[65536];
  const int tc = blockIdx.x, dir = blockIdx.y;
  if (dir == 0 && tc < 16) {                 // zero flags[16][1024] before any k_step
    unsigned* fl = flags + (size_t)tc*1024;
    for (int i = threadIdx.x; i < 1024; i += 512) fl[i] = 0;
  }
  const int p = sbase + tc;
  const int t = dir ? (1023 - p) : p;
  gx_body(smem, X, dir ? Wb : Wf, dir ? bihb : bihf, dir ? bhhb : bhhf,
          gxc, CT, tc, dir, t);
}

// ---------------- merged step: rec(chunk c, col-split) + gx(chunk c+1) ----------------
__global__ __launch_bounds__(512, 1) void k_step(
    const float* __restrict__ Whh_f, const float* __restrict__ bhh_f,
    const float* __restrict__ Whh_b, const float* __restrict__ bhh_b,
    const _Float16* __restrict__ gxin, float* __restrict__ wsh,
    _Float16* __restrict__ out16, float* __restrict__ hidden,
    char* __restrict__ hxbuf, unsigned* __restrict__ flags,
    int CT, int sbase,
    const float* __restrict__ X,
    const float* __restrict__ Wf, const float* __restrict__ bihf, const float* __restrict__ bhhf,
    const float* __restrict__ Wb, const float* __restrict__ bihb, const float* __restrict__ bhhb,
    _Float16* __restrict__ gxout, int sbase_gx, int gx_valid)
{
  __shared__ char smem[65536];
  if (blockIdx.x >= 16) {                    // ---- gx role: chunk c+1 ----
    if (!gx_valid) return;
    const int b = blockIdx.x - 16;
    const int tc = b >> 1, dir = b & 1;
    const int p = sbase_gx + tc;
    const int t = dir ? (1023 - p) : p;
    gx_body(smem, X, dir ? Wb : Wf, dir ? bihb : bihf, dir ? bhhb : bhhf,
            gxout, CT, tc, dir, t);
    return;
  }
  // ---- recurrence role: block = (col-half ch, pair pr=(dir,bsl)) ----
  const int ch  = blockIdx.x >> 3;
  const int pr  = blockIdx.x & 7;
  const int dir = pr & 1;
  const int bsl = pr >> 1;
  const int bbase = bsl * 16;
  const float* __restrict__ Whh = dir ? Whh_b : Whh_f;
  const float* __restrict__ bhh = dir ? bhh_b : bhh_f;
  const int tid = threadIdx.x, w = tid >> 6, l = tid & 63;
  const int lr = l & 15, g = l >> 4;
  const int j0 = (ch << 7) + w*16;           // +lr = my h column
  // W_hh B-frags, STATICALLY indexed: wfo = own K-half, wfx = other K-half.
  f16x8 wfo[3][4], wfx[3][4];
  #pragma unroll
  for (int ct = 0; ct < 3; ++ct) {
    const int colg = ct*256 + j0 + lr;
    const float scl = (ct < 2) ? NLOG2E : P2LOG2E;
    #pragma unroll
    for (int kko = 0; kko < 4; ++kko) {
      const float4* so = (const float4*)(Whh + (size_t)colg*256 + (ch*4+kko)*32 + g*8);
      wfo[ct][kko] = pack8s(so[0], so[1], scl);
      const float4* sx = (const float4*)(Whh + (size_t)colg*256 + ((ch^1)*4+kko)*32 + g*8);
      wfx[ct][kko] = pack8s(sx[0], sx[1], scl);
    }
  }
  const float bn = P2LOG2E * bhh[512 + j0 + lr];
  // full 16-row x 256-col h tile, ping-pong 2x8KB; own half = bytes [ch*4096,+4096)
  char* const afpo = smem + ch*4096 + l*16;            // own-half af read base
  char* const afpx = smem + (ch^1)*4096 + l*16;        // other-half (chunk-start only)
  char* const hwp  = smem + ch*4096 + w*512 + (lr>>3)*256 + g*64 + (lr&7)*2;
  float hold[4];
  if (sbase == 0) {
    *(int4*)(smem + tid*16) = make_int4(0,0,0,0);      // zero full tile hs[0]
    #pragma unroll
    for (int q = 0; q < 4; ++q) hold[q] = 0.f;
  } else {                                   // restore FULL h tile from prev chunk
    const int r = tid >> 5, kq = tid & 31;
    const float4* s4 = (const float4*)(wsh + ((size_t)(dir*64 + bbase + r))*256 + kq*8);
    *(f16x8*)(smem + (kq>>2)*1024 + (((kq&3)*16) + r)*16) = pack8(s4[0], s4[1]);
    #pragma unroll
    for (int q = 0; q < 4; ++q)
      hold[q] = wsh[((size_t)(dir*64 + bbase + g*4 + q))*256 + j0 + lr];
  }
  __syncthreads();

  const int t0 = dir ? (1023 - sbase) : sbase;
  char* optr = (char*)out16 + ((size_t)t0*64 + bbase + g*4)*1024
             + (size_t)(dir*256 + j0 + lr)*2;
  const ptrdiff_t ostep = dir ? -(ptrdiff_t)65536 : (ptrdiff_t)65536;
  const int tid2 = (ch*4 + (w>>1))*64 + g*16 + lr;
  const _Float16* gp = gxin + ((size_t)(dir*CT)*4 + bsl)*12288
                     + (size_t)tid2*24 + (w&1)*4;
  char* const hxme = hxbuf + (size_t)(pr*2 + ch)*8192;        // my linear half-tile
  const char* const hxot = hxbuf + (size_t)(pr*2 + (ch^1))*8192;
  unsigned* const myflag = flags + (size_t)blockIdx.x*1024;
  unsigned* const pflag  = flags + (size_t)(blockIdx.x ^ 8)*1024;
  char* const cpsrc = smem + ch*4096 + tid*8;                 // LDS->hx copy source
  int sabs = sbase;

// Step: gv loads -> [spin pflag(s-1); acq fence; 8 u64 od loads] -> own-half
// MFMA (hides od) -> other-half MFMA (od bit_cast / LDS at chunk start) ->
// gates -> own LDS tile write -> bar#1 -> LDS->hx linear copy (u64 atomics) ->
// bar#2 (acks) -> tid0 release flag -> out16 stores (fire & forget).
#define REC_STEP(RB, FIRST)                                                        \
  {                                                                                \
    const f16x4 gv0 = *(const f16x4*)(gp);                                         \
    const f16x4 gv1 = *(const f16x4*)(gp + 8);                                     \
    const f16x4 gv2 = *(const f16x4*)(gp + 16);                                    \
    gp += 49152;                                                                   \
    u64x2 od0, od1, od2, od3;                                                      \
    if (!(FIRST)) {                                                                \
      while (!__hip_atomic_load(pflag + (sabs-1), __ATOMIC_RELAXED,                \
                                __HIP_MEMORY_SCOPE_AGENT)) {}                      \
      __builtin_amdgcn_fence(__ATOMIC_ACQUIRE, "agent");                           \
      const char* ob = hxot + ((sabs-1)&1)*4096 + l*16;                            \
      od0[0] = __hip_atomic_load((const u64_t*)(ob),          __ATOMIC_RELAXED, __HIP_MEMORY_SCOPE_AGENT); \
      od0[1] = __hip_atomic_load((const u64_t*)(ob+8),        __ATOMIC_RELAXED, __HIP_MEMORY_SCOPE_AGENT); \
      od1[0] = __hip_atomic_load((const u64_t*)(ob+1024),     __ATOMIC_RELAXED, __HIP_MEMORY_SCOPE_AGENT); \
      od1[1] = __hip_atomic_load((const u64_t*)(ob+1032),     __ATOMIC_RELAXED, __HIP_MEMORY_SCOPE_AGENT); \
      od2[0] = __hip_atomic_load((const u64_t*)(ob+2048),     __ATOMIC_RELAXED, __HIP_MEMORY_SCOPE_AGENT); \
      od2[1] = __hip_atomic_load((const u64_t*)(ob+2056),     __ATOMIC_RELAXED, __HIP_MEMORY_SCOPE_AGENT); \
      od3[0] = __hip_atomic_load((const u64_t*)(ob+3072),     __ATOMIC_RELAXED, __HIP_MEMORY_SCOPE_AGENT); \
      od3[1] = __hip_atomic_load((const u64_t*)(ob+3080),     __ATOMIC_RELAXED, __HIP_MEMORY_SCOPE_AGENT); \
    }                                                                              \
    f32x4 ar = (f32x4){0.f,0.f,0.f,0.f};                                           \
    f32x4 az = (f32x4){0.f,0.f,0.f,0.f};                                           \
    f32x4 an = (f32x4){bn,bn,bn,bn};                                               \
    _Pragma("unroll")                                                              \
    for (int kko = 0; kko < 4; ++kko) {      /* own half: LDS, hides od */         \
      const f16x8 af = *(const f16x8*)(afpo + (RB)*8192 + kko*1024);               \
      ar = MFMA(af, wfo[0][kko], ar);                                              \
      az = MFMA(af, wfo[1][kko], az);                                              \
      an = MFMA(af, wfo[2][kko], an);                                              \
    }                                                                              \
    if (FIRST) {                                                                   \
      _Pragma("unroll")                                                            \
      for (int kko = 0; kko < 4; ++kko) {                                          \
        const f16x8 af = *(const f16x8*)(afpx + (RB)*8192 + kko*1024);             \
        ar = MFMA(af, wfx[0][kko], ar);                                            \
        az = MFMA(af, wfx[1][kko], az);                                            \
        an = MFMA(af, wfx[2][kko], an);                                            \
      }                                                                            \
    } else {                                                                       \
      const f16x8 a0 = __builtin_bit_cast(f16x8, od0);                             \
      ar = MFMA(a0, wfx[0][0], ar); az = MFMA(a0, wfx[1][0], az);                  \
      an = MFMA(a0, wfx[2][0], an);                                                \
      const f16x8 a1 = __builtin_bit_cast(f16x8, od1);                             \
      ar = MFMA(a1, wfx[0][1], ar); az = MFMA(a1, wfx[1][1], az);                  \
      an = MFMA(a1, wfx[2][1], an);                                                \
      const f16x8 a2 = __builtin_bit_cast(f16x8, od2);                             \
      ar = MFMA(a2, wfx[0][2], ar); az = MFMA(a2, wfx[1][2], az);                  \
      an = MFMA(a2, wfx[2][2], an);                                                \
      const f16x8 a3 = __builtin_bit_cast(f16x8, od3);                             \
      ar = MFMA(a3, wfx[0][3], ar); az = MFMA(a3, wfx[1][3], az);                  \
      an = MFMA(a3, wfx[2][3], an);                                                \
    }                                                                              \
    f16x4 houts;                                                                   \
    _Pragma("unroll")                                                              \
    for (int q = 0; q < 4; ++q) {                                                  \
      const float rv = __builtin_amdgcn_rcpf(                                      \
          1.f + __builtin_amdgcn_exp2f((float)gv0[q] + ar[q]));                    \
      const float zv = __builtin_amdgcn_rcpf(                                      \
          1.f + __builtin_amdgcn_exp2f((float)gv1[q] + az[q]));                    \
      const float nv = __builtin_fmaf(-2.f, __builtin_amdgcn_rcpf(                 \
          1.f + __builtin_amdgcn_exp2f(                                            \
              __builtin_fmaf(rv, an[q], (float)gv2[q]))), 1.f);                    \
      const float h = __builtin_fmaf(zv, hold[q] - nv, nv);                        \
      hold[q] = h;                                                                 \
      const _Float16 hf = (_Float16)h;                                             \
      houts[q] = hf;                                                               \
      *(_Float16*)(hwp + ((RB)^1)*8192 + q*16) = hf;                               \
    }                                                                              \
    __syncthreads();                         /* bar#1: own LDS half-tile done */   \
    {                                                                              \
      const u64_t cv = *(const u64_t*)(cpsrc + ((RB)^1)*8192);                     \
      __hip_atomic_store((u64_t*)(hxme + (sabs&1)*4096 + tid*8), cv,               \
                         __ATOMIC_RELAXED, __HIP_MEMORY_SCOPE_AGENT);              \
    }                                                                              \
    __syncthreads();                         /* bar#2: hx stores acked */          \
    if (tid == 0)                                                                  \
      __hip_atomic_store(myflag + sabs, 1u, __ATOMIC_RELEASE,                      \
                         __HIP_MEMORY_SCOPE_AGENT);                                \
    _Pragma("unroll")                                                              \
    for (int q = 0; q < 4; ++q)              /* out16: fire & forget */            \
      *(_Float16*)(optr + q*1024) = houts[q];                                      \
    optr += ostep;                                                                 \
    ++sabs;                                                                        \
  }

  REC_STEP(0, 1)                             // first step: other half from LDS
  #pragma unroll 1
  for (int sc = 1; sc + 1 < CT; sc += 2) {
    REC_STEP(1, 0)
    REC_STEP(0, 0)
  }
  REC_STEP(1, 0)
#undef REC_STEP

  if (sbase + CT == 1024) {                  // final h -> hidden output (own cols)
    #pragma unroll
    for (int q = 0; q < 4; ++q)
      hidden[((size_t)(dir*64 + bbase + g*4 + q))*256 + j0 + lr] = hold[q];
  } else {                                   // persist own cols for next chunk
    #pragma unroll
    for (int q = 0; q < 4; ++q)
      wsh[((size_t)(dir*64 + bbase + g*4 + q))*256 + j0 + lr] = hold[q];
  }
}

// ---------------- FC in place: relu(concat_f16 @ W_fc^T + b) -> f32 ----------------
__global__ __launch_bounds__(256) void k_fc(
    const _Float16* __restrict__ h16, const float* __restrict__ Wfc,
    const float* __restrict__ bfc, float* __restrict__ out)
{
  const int mt = blockIdx.x;
  __shared__ _Float16 As[64*512];            // 64KB
  const int tid = threadIdx.x, w = tid >> 6, l = tid & 63;
  const int lr = l & 15, g = l >> 4;
  #pragma unroll
  for (int i = 0; i < 16; ++i) {
    int c = tid + i*256, r = c >> 6, cc = c & 63;
    *(int4*)((char*)As + SWZ2(r, cc*16)) =
        *(const int4*)((const char*)h16 + ((size_t)mt*64 + r)*1024 + cc*16);
  }
  __syncthreads();                           // all h16 reads drained before any store
  #pragma unroll 1
  for (int nt = 0; nt < 4; ++nt) {
    f32x4 acc[4];
    #pragma unroll
    for (int ct = 0; ct < 4; ++ct) acc[ct] = (f32x4){0.f,0.f,0.f,0.f};
    #pragma unroll 2
    for (int kk = 0; kk < 16; ++kk) {
      f16x8 af = *(const f16x8*)((const char*)As + SWZ2(w*16 + lr, kk*64 + g*16));
      #pragma unroll
      for (int ct = 0; ct < 4; ++ct) {
        const float4* s4 = (const float4*)(Wfc + (size_t)(nt*64 + ct*16 + lr)*512 + kk*32 + g*8);
        acc[ct] = MFMA(af, pack8(s4[0], s4[1]), acc[ct]);
      }
    }
    #pragma unroll
    for (int ct = 0; ct < 4; ++ct) {
      const int col = nt*64 + ct*16 + lr;
      const float bv = bfc[col];
      #pragma unroll
      for (int q = 0; q < 4; ++q) {
        const int row = w*16 + g*4 + q;
        out[((size_t)mt*64 + row)*256 + col] = fmaxf(acc[ct][q] + bv, 0.f);
      }
    }
  }
}

extern "C" void kernel_launch(void* const* d_in, const int* in_sizes, int n_in,
                              void* d_out, int out_size, void* d_ws, size_t ws_size,
                              hipStream_t stream) {
  const float* X      = (const float*)d_in[0];
  const float* W_ih_f = (const float*)d_in[1];
  const float* W_hh_f = (const float*)d_in[2];
  const float* b_ih_f = (const float*)d_in[3];
  const float* b_hh_f = (const float*)d_in[4];
  const float* W_ih_b = (const float*)d_in[5];
  const float* W_hh_b = (const float*)d_in[6];
  const float* b_ih_b = (const float*)d_in[7];
  const float* b_hh_b = (const float*)d_in[8];
  const float* W_fc   = (const float*)d_in[9];
  const float* b_fc   = (const float*)d_in[10];

  // ws: buf0 | buf1 | wsh 128KB | hx 128KB | flags 64KB
  int CT = 256;
  while (CT > 8 && (2*(size_t)CT*196608 + 327680) > ws_size) CT >>= 1;
  const size_t CTB = (size_t)CT*196608;
  _Float16* buf0  = (_Float16*)d_ws;
  _Float16* buf1  = (_Float16*)((char*)d_ws + CTB);
  float*    wsh   = (float*)((char*)d_ws + 2*CTB);
  char*     hx    = (char*)d_ws + 2*CTB + 131072;
  unsigned* flags = (unsigned*)((char*)d_ws + 2*CTB + 262144);

  _Float16* h16   = (_Float16*)d_out;                  // [1024][64][512] f16 (in-place)
  float*    out   = (float*)d_out;                     // [1024][64][256] f32
  float*    hidden= (float*)d_out + (size_t)1024*64*256;

  const int NC = 1024 / CT;
  k_gx0<<<dim3(CT, 2), dim3(512), 0, stream>>>(X, W_ih_f, b_ih_f, b_hh_f,
                                               W_ih_b, b_ih_b, b_hh_b, buf0, CT, 0, flags);
  for (int c = 0; c < NC; ++c) {
    _Float16* bin  = (c & 1) ? buf1 : buf0;
    _Float16* bout = (c & 1) ? buf0 : buf1;
    k_step<<<dim3(16 + 2*CT), dim3(512), 0, stream>>>(
        W_hh_f, b_hh_f, W_hh_b, b_hh_b, bin, wsh, h16, hidden, hx, flags,
        CT, c*CT,
        X, W_ih_f, b_ih_f, b_hh_f, W_ih_b, b_ih_b, b_hh_b,
        bout, (c+1)*CT, (c < NC-1) ? 1 : 0);
  }
  k_fc<<<dim3(1024), dim3(256), 0, stream>>>(h16, W_fc, b_fc, out);
}

// Round 14
// 2088.404 us; speedup vs baseline: 4.7003x; 1.5332x over previous
//
#include <hip/hip_runtime.h>
#include <hip/hip_fp16.h>

// Bidirectional GRU (B=64,S=1024,E=H=256) + FC/ReLU head.
// r14 = r10 + fc merged with CORRECT bidirectional coverage: out16[t] is
// complete only when fwd (t<done_f) AND bwd (t>=1024-done_b) have written.
// With CT=256 the first nonempty intersection is t in [256,768) before
// k_step(3); the rest goes to fc_tail. Host tracks fc'd interval [flo,fhi)
// and passes <=2 new segments per launch.
//   k_gx0(chunk0) ; k_step(c): [blk 0-7]=rec(c), [8..8+2CT)=gx(c+1),
//                              [8+2CT..)=fc(new segments)   ; k_fc_tail(rest)
// rec: 8 WGs (2dir x 4bsl) x 512thr, launch_bounds(512,2), W_hh f16 frags
// reg-resident (pre-scaled -log2e / 2log2e, exp2 gates), h in LDS in
// MFMA-A-frag order (linear conflict-free ds_read_b128), ping-pong tiles,
// one lgkm-only raw barrier/step, immediate out16 stores (f16 into d_out;
// fc converts in place to f32 once both directions have written the row).

typedef _Float16 f16x8 __attribute__((ext_vector_type(8)));
typedef _Float16 f16x4 __attribute__((ext_vector_type(4)));
typedef float    f32x4 __attribute__((ext_vector_type(4)));

#define MFMA(a,b,c) __builtin_amdgcn_mfma_f32_16x16x32_f16((a),(b),(c),0,0,0)
#define SWZ(r,c)  ((((r)*512)  + (c)) ^ (((r)&7)<<4))
#define SWZ2(r,c) ((((r)*1024) + (c)) ^ (((r)&7)<<4))
#define NLOG2E (-1.442695041f)
#define P2LOG2E (2.885390082f)

__device__ inline f16x8 pack8(float4 a, float4 b){
  f16x8 h;
  h[0]=(_Float16)a.x; h[1]=(_Float16)a.y; h[2]=(_Float16)a.z; h[3]=(_Float16)a.w;
  h[4]=(_Float16)b.x; h[5]=(_Float16)b.y; h[6]=(_Float16)b.z; h[7]=(_Float16)b.w;
  return h;
}
__device__ inline f16x8 pack8s(float4 a, float4 b, float s){
  f16x8 h;
  h[0]=(_Float16)(a.x*s); h[1]=(_Float16)(a.y*s); h[2]=(_Float16)(a.z*s); h[3]=(_Float16)(a.w*s);
  h[4]=(_Float16)(b.x*s); h[5]=(_Float16)(b.y*s); h[6]=(_Float16)(b.z*s); h[7]=(_Float16)(b.w*s);
  return h;
}

// ---------------- gx body: 512 threads, one (t,dir); waves 4-7 stage-only ----------------
__device__ __forceinline__ void gx_body(
    char* smem, const float* __restrict__ X,
    const float* __restrict__ Wp, const float* __restrict__ bi, const float* __restrict__ bh,
    _Float16* __restrict__ gxc, int CT, int tc, int dir, int t)
{
  _Float16* As = (_Float16*)smem;            // 32KB
  _Float16* Bs = (_Float16*)(smem + 32768);  // 32KB
  const int tid = threadIdx.x;
  #pragma unroll
  for (int i = 0; i < 4; ++i) {              // stage A: rows = batch b, fixed t
    int c = tid + i*512, r = c >> 5, cc = c & 31;
    const float4* s4 = (const float4*)(X + ((size_t)r*1024 + t)*256 + cc*8);
    *(f16x8*)((char*)As + SWZ(r, cc*16)) = pack8(s4[0], s4[1]);
  }
  const int w = tid >> 6, l = tid & 63, lr = l & 15, g = l >> 4;
  const size_t obase = (((size_t)dir*CT + tc)*4 + (w & 3)) * (size_t)12288;
  #pragma unroll 1
  for (int nt = 0; nt < 12; ++nt) {
    __syncthreads();
    #pragma unroll
    for (int i = 0; i < 4; ++i) {            // stage B: W rows nt*64..+64
      int c = tid + i*512, r = c >> 5, cc = c & 31;
      const float4* s4 = (const float4*)(Wp + (size_t)(nt*64 + r)*256 + cc*8);
      *(f16x8*)((char*)Bs + SWZ(r, cc*16)) = pack8(s4[0], s4[1]);
    }
    __syncthreads();
    if (w < 4) {
      f32x4 acc[4];
      #pragma unroll
      for (int ct = 0; ct < 4; ++ct) acc[ct] = (f32x4){0.f,0.f,0.f,0.f};
      #pragma unroll
      for (int kk = 0; kk < 8; ++kk) {
        f16x8 af = *(const f16x8*)((const char*)As + SWZ(w*16 + lr, kk*64 + g*16));
        #pragma unroll
        for (int ct = 0; ct < 4; ++ct) {
          f16x8 bfr = *(const f16x8*)((const char*)Bs + SWZ(ct*16 + lr, kk*64 + g*16));
          acc[ct] = MFMA(af, bfr, acc[ct]);
        }
      }
      #pragma unroll
      for (int ct = 0; ct < 4; ++ct) {       // consumer layout [tid512][3][8]
        const int col = nt*64 + ct*16 + lr;
        const int gate = col >> 8;
        const float sc = (gate == 2) ? P2LOG2E : NLOG2E;
        const float bv = bi[col] + (gate < 2 ? bh[col] : 0.f);
        const int j = col & 255;
        const int tid2 = (j>>5)*64 + g*16 + (j&15);
        const int off = ((j>>4)&1)*4;
        f16x4 v;
        #pragma unroll
        for (int q = 0; q < 4; ++q) v[q] = (_Float16)((acc[ct][q] + bv)*sc);
        *(f16x4*)(gxc + obase + (size_t)tid2*24 + gate*8 + off) = v;
      }
    }
  }
}

// ---------------- fc body: 512 threads, one t; relu(concat_f16 @ Wfc^T + b) in place ----------------
__device__ __forceinline__ void fc_body(
    char* smem, const _Float16* __restrict__ h16, const float* __restrict__ Wfc,
    const float* __restrict__ bfc, float* __restrict__ out, int mt)
{
  _Float16* As = (_Float16*)smem;            // 64KB: [64 rows][512 cols]
  const int tid = threadIdx.x, w = tid >> 6, l = tid & 63;
  const int lr = l & 15, g = l >> 4;
  #pragma unroll
  for (int i = 0; i < 8; ++i) {
    int c = tid + i*512, r = c >> 6, cc = c & 63;
    *(int4*)((char*)As + SWZ2(r, cc*16)) =
        *(const int4*)((const char*)h16 + ((size_t)mt*64 + r)*1024 + cc*16);
  }
  __syncthreads();                           // all h16 reads drained before any store
  const int w4 = w & 3;                      // row-group (rows w4*16..+16)
  const int nb = (w >> 2) * 2;               // nt pair: waves 0-3 -> {0,1}, 4-7 -> {2,3}
  #pragma unroll 1
  for (int ni = 0; ni < 2; ++ni) {
    const int nt = nb + ni;
    f32x4 acc[4];
    #pragma unroll
    for (int ct = 0; ct < 4; ++ct) acc[ct] = (f32x4){0.f,0.f,0.f,0.f};
    #pragma unroll 2
    for (int kk = 0; kk < 16; ++kk) {
      f16x8 af = *(const f16x8*)((const char*)As + SWZ2(w4*16 + lr, kk*64 + g*16));
      #pragma unroll
      for (int ct = 0; ct < 4; ++ct) {
        const float4* s4 = (const float4*)(Wfc + (size_t)(nt*64 + ct*16 + lr)*512 + kk*32 + g*8);
        acc[ct] = MFMA(af, pack8(s4[0], s4[1]), acc[ct]);
      }
    }
    #pragma unroll
    for (int ct = 0; ct < 4; ++ct) {
      const int col = nt*64 + ct*16 + lr;
      const float bv = bfc[col];
      #pragma unroll
      for (int q = 0; q < 4; ++q) {
        const int row = w4*16 + g*4 + q;
        out[((size_t)mt*64 + row)*256 + col] = fmaxf(acc[ct][q] + bv, 0.f);
      }
    }
  }
}

// ---------------- gx prologue kernel (chunk 0) ----------------
__global__ __launch_bounds__(512, 2) void k_gx0(
    const float* __restrict__ X,
    const float* __restrict__ Wf, const float* __restrict__ bihf, const float* __restrict__ bhhf,
    const float* __restrict__ Wb, const float* __restrict__ bihb, const float* __restrict__ bhhb,
    _Float16* __restrict__ gxc, int CT, int sbase)
{
  __shared__ char smem[65536];
  const int tc = blockIdx.x, dir = blockIdx.y;
  const int p = sbase + tc;
  const int t = dir ? (1023 - p) : p;
  gx_body(smem, X, dir ? Wb : Wf, dir ? bihb : bihf, dir ? bhhb : bhhf,
          gxc, CT, tc, dir, t);
}

// ---------------- merged step: rec(c) + gx(c+1) + fc(ready rows) ----------------
__global__ __launch_bounds__(512, 2) void k_step(
    const float* __restrict__ Whh_f, const float* __restrict__ bhh_f,
    const float* __restrict__ Whh_b, const float* __restrict__ bhh_b,
    const _Float16* __restrict__ gxin, float* __restrict__ wsh,
    _Float16* __restrict__ out16, float* __restrict__ hidden,
    int CT, int sbase,
    const float* __restrict__ X,
    const float* __restrict__ Wf, const float* __restrict__ bihf, const float* __restrict__ bhhf,
    const float* __restrict__ Wb, const float* __restrict__ bihb, const float* __restrict__ bhhb,
    _Float16* __restrict__ gxout, int sbase_gx, int gx_valid,
    const float* __restrict__ Wfc, const float* __restrict__ bfc,
    float* __restrict__ outf, int fb1, int fn1, int fb2)
{
  __shared__ char smem[65536];
  if (blockIdx.x >= (unsigned)(8 + 2*CT)) {  // ---- fc role: rows both dirs wrote ----
    const int i = blockIdx.x - (8 + 2*CT);
    const int mt = (i < fn1) ? (fb1 + i) : (fb2 + (i - fn1));
    fc_body(smem, out16, Wfc, bfc, outf, mt);
    return;
  }
  if (blockIdx.x >= 8) {                     // ---- gx role: chunk c+1 ----
    if (!gx_valid) return;
    const int b = blockIdx.x - 8;
    const int tc = b >> 1, dir = b & 1;
    const int p = sbase_gx + tc;
    const int t = dir ? (1023 - p) : p;
    gx_body(smem, X, dir ? Wb : Wf, dir ? bihb : bihf, dir ? bhhb : bhhf,
            gxout, CT, tc, dir, t);
    return;
  }
  // ---- recurrence role (blocks 0-7) ----
  const int dir = blockIdx.x & 1;
  const int bsl = blockIdx.x >> 1;
  const int bbase = bsl * 16;
  const float* __restrict__ Whh = dir ? Whh_b : Whh_f;
  const float* __restrict__ bhh = dir ? bhh_b : bhh_f;
  const int tid = threadIdx.x, w = tid >> 6, l = tid & 63;
  const int lr = l & 15, g = l >> 4;
  const int j0 = w * 32;
  f16x8 wf[6][8];                            // B-frag: W[col][k=kk*32+g*8+i], pre-scaled
  #pragma unroll
  for (int ct = 0; ct < 6; ++ct) {
    const int colg = (ct>>1)*256 + j0 + (ct&1)*16 + lr;
    const float scl = (ct < 4) ? NLOG2E : P2LOG2E;
    #pragma unroll
    for (int kk = 0; kk < 8; ++kk) {
      const float4* s4 = (const float4*)(Whh + (size_t)colg*256 + kk*32 + g*8);
      wf[ct][kk] = pack8s(s4[0], s4[1], scl);
    }
  }
  const float bn0 = P2LOG2E * bhh[512 + j0 + lr];
  const float bn1 = P2LOG2E * bhh[512 + j0 + 16 + lr];
  char* const hsb = smem;                    // ping-pong A-frag h tiles (16KB used)
  char* const afp = hsb + l*16;
  char* const hwp = hsb + w*1024 + (lr>>3)*256 + g*64 + (lr&7)*2;
  float hold[2][4];
  if (sbase == 0) {
    *(int4*)(hsb + tid*16) = make_int4(0,0,0,0);
    #pragma unroll
    for (int jt = 0; jt < 2; ++jt)
      #pragma unroll
      for (int q = 0; q < 4; ++q) hold[jt][q] = 0.f;
  } else {
    const int r = tid >> 5, kq = tid & 31;
    const float4* s4 = (const float4*)(wsh + ((size_t)(dir*64 + bbase + r))*256 + kq*8);
    *(f16x8*)(hsb + (kq>>2)*1024 + (((kq&3)*16) + r)*16) = pack8(s4[0], s4[1]);
    #pragma unroll
    for (int jt = 0; jt < 2; ++jt)
      #pragma unroll
      for (int q = 0; q < 4; ++q)
        hold[jt][q] = wsh[((size_t)(dir*64 + bbase + g*4 + q))*256 + j0 + jt*16 + lr];
  }
  __syncthreads();

  const int t0 = dir ? (1023 - sbase) : sbase;
  char* optr = (char*)out16 + ((size_t)t0*64 + bbase + g*4)*1024
             + (size_t)(dir*256 + j0 + lr)*2;
  const ptrdiff_t ostep = dir ? -(ptrdiff_t)65536 : (ptrdiff_t)65536;
  const _Float16* gp = gxin + ((size_t)(dir*CT)*4 + bsl)*12288 + (size_t)tid*24;
  const ptrdiff_t gstep = 4*12288;

#define REC_STEP(RB)                                                               \
  {                                                                                \
    const f16x8 gv0 = *(const f16x8*)(gp);                                         \
    const f16x8 gv1 = *(const f16x8*)(gp + 8);                                     \
    const f16x8 gv2 = *(const f16x8*)(gp + 16);                                    \
    gp += gstep;                                                                   \
    {                                                                              \
      f32x4 ar = (f32x4){0.f,0.f,0.f,0.f};                                         \
      f32x4 az = (f32x4){0.f,0.f,0.f,0.f};                                         \
      f32x4 an = (f32x4){bn0,bn0,bn0,bn0};                                         \
      _Pragma("unroll")                                                            \
      for (int kk = 0; kk < 8; ++kk) {                                             \
        const f16x8 af = *(const f16x8*)(afp + (RB)*8192 + kk*1024);               \
        ar = MFMA(af, wf[0][kk], ar);                                              \
        az = MFMA(af, wf[2][kk], az);                                              \
        an = MFMA(af, wf[4][kk], an);                                              \
      }                                                                            \
      _Pragma("unroll")                                                            \
      for (int q = 0; q < 4; ++q) {                                                \
        const float rv = __builtin_amdgcn_rcpf(                                    \
            1.f + __builtin_amdgcn_exp2f((float)gv0[q] + ar[q]));                  \
        const float zv = __builtin_amdgcn_rcpf(                                    \
            1.f + __builtin_amdgcn_exp2f((float)gv1[q] + az[q]));                  \
        const float nv = __builtin_fmaf(-2.f, __builtin_amdgcn_rcpf(               \
            1.f + __builtin_amdgcn_exp2f(                                          \
                __builtin_fmaf(rv, an[q], (float)gv2[q]))), 1.f);                  \
        const float h = __builtin_fmaf(zv, hold[0][q] - nv, nv);                   \
        hold[0][q] = h;                                                            \
        const _Float16 hf = (_Float16)h;                                           \
        *(_Float16*)(hwp + ((RB)^1)*8192 + q*16) = hf;                             \
        *(_Float16*)(optr + q*1024) = hf;                                          \
      }                                                                            \
    }                                                                              \
    {                                                                              \
      f32x4 ar = (f32x4){0.f,0.f,0.f,0.f};                                         \
      f32x4 az = (f32x4){0.f,0.f,0.f,0.f};                                         \
      f32x4 an = (f32x4){bn1,bn1,bn1,bn1};                                         \
      _Pragma("unroll")                                                            \
      for (int kk = 0; kk < 8; ++kk) {                                             \
        const f16x8 af = *(const f16x8*)(afp + (RB)*8192 + kk*1024);               \
        ar = MFMA(af, wf[1][kk], ar);                                              \
        az = MFMA(af, wf[3][kk], az);                                              \
        an = MFMA(af, wf[5][kk], an);                                              \
      }                                                                            \
      _Pragma("unroll")                                                            \
      for (int q = 0; q < 4; ++q) {                                                \
        const float rv = __builtin_amdgcn_rcpf(                                    \
            1.f + __builtin_amdgcn_exp2f((float)gv0[4+q] + ar[q]));                \
        const float zv = __builtin_amdgcn_rcpf(                                    \
            1.f + __builtin_amdgcn_exp2f((float)gv1[4+q] + az[q]));                \
        const float nv = __builtin_fmaf(-2.f, __builtin_amdgcn_rcpf(               \
            1.f + __builtin_amdgcn_exp2f(                                          \
                __builtin_fmaf(rv, an[q], (float)gv2[4+q]))), 1.f);                \
        const float h = __builtin_fmaf(zv, hold[1][q] - nv, nv);                   \
        hold[1][q] = h;                                                            \
        const _Float16 hf = (_Float16)h;                                           \
        *(_Float16*)(hwp + ((RB)^1)*8192 + 512 + q*16) = hf;                       \
        *(_Float16*)(optr + q*1024 + 32) = hf;                                     \
      }                                                                            \
    }                                                                              \
    optr += ostep;                                                                 \
    asm volatile("s_waitcnt lgkmcnt(0)" ::: "memory");                             \
    __builtin_amdgcn_s_barrier();                                                  \
    asm volatile("" ::: "memory");                                                 \
  }

  #pragma unroll 1
  for (int sc = 0; sc < CT; sc += 2) {
    REC_STEP(0)
    REC_STEP(1)
  }
#undef REC_STEP

  if (sbase + CT == 1024) {                  // final h -> hidden output
    #pragma unroll
    for (int jt = 0; jt < 2; ++jt)
      #pragma unroll
      for (int q = 0; q < 4; ++q)
        hidden[((size_t)(dir*64 + bbase + g*4 + q))*256 + j0 + jt*16 + lr] = hold[jt][q];
  } else {                                   // persist h for next chunk
    #pragma unroll
    for (int jt = 0; jt < 2; ++jt)
      #pragma unroll
      for (int q = 0; q < 4; ++q)
        wsh[((size_t)(dir*64 + bbase + g*4 + q))*256 + j0 + jt*16 + lr] = hold[jt][q];
  }
}

// ---------------- fc tail: remaining rows (two segments) ----------------
__global__ __launch_bounds__(512, 2) void k_fc_tail(
    const _Float16* __restrict__ h16, const float* __restrict__ Wfc,
    const float* __restrict__ bfc, float* __restrict__ out,
    int fb1, int fn1, int fb2)
{
  __shared__ char smem[65536];
  const int i = blockIdx.x;
  const int mt = (i < fn1) ? (fb1 + i) : (fb2 + (i - fn1));
  fc_body(smem, h16, Wfc, bfc, out, mt);
}

extern "C" void kernel_launch(void* const* d_in, const int* in_sizes, int n_in,
                              void* d_out, int out_size, void* d_ws, size_t ws_size,
                              hipStream_t stream) {
  const float* X      = (const float*)d_in[0];
  const float* W_ih_f = (const float*)d_in[1];
  const float* W_hh_f = (const float*)d_in[2];
  const float* b_ih_f = (const float*)d_in[3];
  const float* b_hh_f = (const float*)d_in[4];
  const float* W_ih_b = (const float*)d_in[5];
  const float* W_hh_b = (const float*)d_in[6];
  const float* b_ih_b = (const float*)d_in[7];
  const float* b_hh_b = (const float*)d_in[8];
  const float* W_fc   = (const float*)d_in[9];
  const float* b_fc   = (const float*)d_in[10];

  // gxc double-buffered; ws need = 2*CT*196608 + 131072 (CT=256 -> 100.8MB).
  int CT = 256;
  while (CT > 8 && (2*(size_t)CT*196608 + 131072) > ws_size) CT >>= 1;
  const size_t CTB = (size_t)CT*196608;
  _Float16* buf0 = (_Float16*)d_ws;
  _Float16* buf1 = (_Float16*)((char*)d_ws + CTB);
  float*    wsh  = (float*)((char*)d_ws + 2*CTB);

  _Float16* h16   = (_Float16*)d_out;                  // [1024][64][512] f16 (in-place)
  float*    out   = (float*)d_out;                     // [1024][64][256] f32
  float*    hidden= (float*)d_out + (size_t)1024*64*256;

  const int NC = 1024 / CT;
  k_gx0<<<dim3(CT, 2), dim3(512), 0, stream>>>(X, W_ih_f, b_ih_f, b_hh_f,
                                               W_ih_b, b_ih_b, b_hh_b, buf0, CT, 0);
  int flo = 512, fhi = 512;                  // fc'd interval [flo,fhi)
  for (int c = 0; c < NC; ++c) {
    _Float16* bin  = (c & 1) ? buf1 : buf0;
    _Float16* bout = (c & 1) ? buf0 : buf1;
    // rows complete before this launch: fwd [0,c*CT), bwd [1024-c*CT,1024)
    const int alo = 1024 - c*CT, ahi = c*CT;
    int b1 = 0, n1 = 0, b2 = 0, n2 = 0;
    if (ahi > alo) {
      if (alo < flo) { b1 = alo; n1 = flo - alo; }
      if (ahi > fhi) { b2 = fhi; n2 = ahi - fhi; }
      if (alo < flo) flo = alo;
      if (ahi > fhi) fhi = ahi;
    }
    k_step<<<dim3(8 + 2*CT + n1 + n2), dim3(512), 0, stream>>>(
        W_hh_f, b_hh_f, W_hh_b, b_hh_b, bin, wsh, h16, hidden, CT, c*CT,
        X, W_ih_f, b_ih_f, b_hh_f, W_ih_b, b_ih_b, b_hh_b,
        bout, (c+1)*CT, (c < NC-1) ? 1 : 0,
        W_fc, b_fc, out, b1, n1, b2);
  }
  // tail: [0,flo) and [fhi,1024)
  const int tn1 = flo, tn2 = 1024 - fhi;
  if (tn1 + tn2 > 0)
    k_fc_tail<<<dim3(tn1 + tn2), dim3(512), 0, stream>>>(h16, W_fc, b_fc, out,
                                                         0, tn1, fhi);
}